// Round 1
// baseline (125.806 us; speedup 1.0000x reference)
//
#include <hip/hip_runtime.h>

#define CHUNK 4096
#define BLOCK 256

__device__ __forceinline__ float wave_incl_scan(float v, int lane) {
#pragma unroll
    for (int off = 1; off < 64; off <<= 1) {
        float u = __shfl_up(v, off);
        if (lane >= off) v += u;
    }
    return v;
}

__device__ __forceinline__ float wave_reduce(float v) {
#pragma unroll
    for (int off = 32; off >= 1; off >>= 1) v += __shfl_down(v, off);
    return v;  // valid in lane 0
}

// Pass A: per-block (contiguous 4096-element chunk) sum of d = x0 - x1
__global__ __launch_bounds__(BLOCK) void k_partial(const float* __restrict__ x0,
                                                   const float* __restrict__ x1,
                                                   float* __restrict__ partials,
                                                   int n) {
    const int t = threadIdx.x;
    const int lane = t & 63;
    const int wave = t >> 6;
    const long base = (long)blockIdx.x * CHUNK;
    float s = 0.f;
#pragma unroll
    for (int k = 0; k < CHUNK / (BLOCK * 4); ++k) {
        long idx = base + (long)(k * BLOCK + t) * 4;
        if (idx + 3 < n) {
            float4 a = *reinterpret_cast<const float4*>(x0 + idx);
            float4 b = *reinterpret_cast<const float4*>(x1 + idx);
            s += (a.x - b.x) + (a.y - b.y) + (a.z - b.z) + (a.w - b.w);
        } else {
#pragma unroll
            for (int j = 0; j < 4; ++j) {
                long i = idx + j;
                if (i < n) s += x0[i] - x1[i];
            }
        }
    }
    s = wave_reduce(s);
    __shared__ float ws[BLOCK / 64];
    if (lane == 0) ws[wave] = s;
    __syncthreads();
    if (t == 0) {
        float tot = 0.f;
#pragma unroll
        for (int w = 0; w < BLOCK / 64; ++w) tot += ws[w];
        partials[blockIdx.x] = tot;
    }
}

// Pass B: single-block exclusive scan of up to 2048 partials (in place)
__global__ __launch_bounds__(BLOCK) void k_scan(float* __restrict__ partials, int B) {
    const int t = threadIdx.x;
    const int lane = t & 63;
    const int wave = t >> 6;
    const int P = 8;  // 256 * 8 = 2048 max partials
    float vex[P];     // local exclusive prefixes
    float run = 0.f;
#pragma unroll
    for (int j = 0; j < P; ++j) {
        int i = t * P + j;
        float x = (i < B) ? partials[i] : 0.f;
        vex[j] = run;
        run += x;
    }
    float tsum = run;
    float inc = wave_incl_scan(tsum, lane);
    __shared__ float wtot[BLOCK / 64];
    if (lane == 63) wtot[wave] = inc;
    __syncthreads();
    float wexcl = 0.f;
    for (int w = 0; w < wave; ++w) wexcl += wtot[w];
    float texcl = wexcl + (inc - tsum);  // exclusive offset for this thread
#pragma unroll
    for (int j = 0; j < P; ++j) {
        int i = t * P + j;
        if (i < B) partials[i] = texcl + vex[j];
    }
}

// Pass C: recompute local prefix, add block offset, accumulate |CDF|
__global__ __launch_bounds__(BLOCK) void k_emd(const float* __restrict__ x0,
                                               const float* __restrict__ x1,
                                               const float* __restrict__ offsets,
                                               float* __restrict__ out, int n) {
    const int t = threadIdx.x;
    const int lane = t & 63;
    const int wave = t >> 6;
    const long base = (long)blockIdx.x * CHUNK;
    __shared__ float wsum[BLOCK / 64];
    float run = offsets[blockIdx.x];
    float acc = 0.f;
#pragma unroll
    for (int k = 0; k < CHUNK / (BLOCK * 4); ++k) {
        long idx = base + (long)(k * BLOCK + t) * 4;
        float d0 = 0.f, d1 = 0.f, d2 = 0.f, d3 = 0.f;
        int valid = 0;
        if (idx + 3 < n) {
            float4 a = *reinterpret_cast<const float4*>(x0 + idx);
            float4 b = *reinterpret_cast<const float4*>(x1 + idx);
            d0 = a.x - b.x; d1 = a.y - b.y; d2 = a.z - b.z; d3 = a.w - b.w;
            valid = 4;
        } else {
            if (idx + 0 < n) { d0 = x0[idx + 0] - x1[idx + 0]; valid = 1; }
            if (idx + 1 < n) { d1 = x0[idx + 1] - x1[idx + 1]; valid = 2; }
            if (idx + 2 < n) { d2 = x0[idx + 2] - x1[idx + 2]; valid = 3; }
        }
        // thread-local inclusive prefix over 4 elements
        float p0 = d0, p1 = p0 + d1, p2 = p1 + d2, p3 = p2 + d3;
        float inc = wave_incl_scan(p3, lane);
        if (lane == 63) wsum[wave] = inc;
        __syncthreads();
        float wexcl = 0.f, ctot = 0.f;
#pragma unroll
        for (int w = 0; w < BLOCK / 64; ++w) {
            float x = wsum[w];
            ctot += x;
            if (w < wave) wexcl += x;
        }
        float boff = run + wexcl + (inc - p3);
        if (valid > 0) acc += fabsf(boff + p0);
        if (valid > 1) acc += fabsf(boff + p1);
        if (valid > 2) acc += fabsf(boff + p2);
        if (valid > 3) acc += fabsf(boff + p3);
        run += ctot;
        __syncthreads();  // wsum reused next iteration
    }
    acc = wave_reduce(acc);
    __shared__ float wacc[BLOCK / 64];
    if (lane == 0) wacc[wave] = acc;
    __syncthreads();
    if (t == 0) {
        float tot = 0.f;
#pragma unroll
        for (int w = 0; w < BLOCK / 64; ++w) tot += wacc[w];
        atomicAdd(out, tot);
    }
}

extern "C" void kernel_launch(void* const* d_in, const int* in_sizes, int n_in,
                              void* d_out, int out_size, void* d_ws, size_t ws_size,
                              hipStream_t stream) {
    const float* x = (const float*)d_in[0];
    const int total = in_sizes[0];
    const int n = total / 2;  // 8388608
    const float* x0 = x;
    const float* x1 = x + n;
    float* out = (float*)d_out;
    float* partials = (float*)d_ws;

    const int B = (n + CHUNK - 1) / CHUNK;  // 2048 for n = 2^23

    hipMemsetAsync(out, 0, sizeof(float), stream);
    k_partial<<<B, BLOCK, 0, stream>>>(x0, x1, partials, n);
    k_scan<<<1, BLOCK, 0, stream>>>(partials, B);
    k_emd<<<B, BLOCK, 0, stream>>>(x0, x1, partials, out, n);
}